// Round 6
// baseline (217.616 us; speedup 1.0000x reference)
//
#include <hip/hip_runtime.h>
#include <cstdint>

// CausalSelfAttention B=2 L=2048 D=1024 H=16 dh=64, fp32 in/out.
// Round 6 = R5 +
//   - single merged prep kernel (cast + 3 transposes), 1 launch not 4
//   - gemm_out 128x64 tiles (512 blocks = 2/CU, LDS 24KB)
//   - attn __launch_bounds__(256,5) to cut VGPR for occupancy

#define LSEQ 2048
#define DM   1024
#define BL   4096   // B * LSEQ

using frag_ab = __attribute__((ext_vector_type(8))) short;     // 8 bf16
using half8   = __attribute__((ext_vector_type(8))) _Float16;  // 8 fp16
using half4   = __attribute__((ext_vector_type(4))) _Float16;
using f32x4   = __attribute__((ext_vector_type(4))) float;

__device__ __forceinline__ unsigned short f2bf(float f) {
  unsigned int u = __float_as_uint(f);
  u += 0x7fffu + ((u >> 16) & 1u);   // RNE (finite inputs only)
  return (unsigned short)(u >> 16);
}

__device__ __forceinline__ void load_lds16(const void* g, void* l) {
  __builtin_amdgcn_global_load_lds(
      (const __attribute__((address_space(1))) unsigned int*)g,
      (__attribute__((address_space(3))) unsigned int*)l, 16, 0, 0);
}

// ---------------- merged prep kernel ----------------
// bid <  4096          : cast x -> bf16 (1 float4 per thread)
// 4096 <= bid < 6144   : W_kq (1024x2048) -> wcat bf16 [2048x1024]
// 6144 <= bid < 7168   : W_v  (1024x1024) -> wcat+2M bf16
// 7168 <= bid < 8192   : W_o  (1024x1024) -> wot fp16

__global__ __launch_bounds__(256) void prep_kernel(
    const float* __restrict__ x, unsigned short* __restrict__ xb,
    const float* __restrict__ W_kq, const float* __restrict__ W_v,
    const float* __restrict__ W_o,
    unsigned short* __restrict__ wcat, _Float16* __restrict__ wot)
{
  const int bid = blockIdx.x;
  const int tid = threadIdx.x;

  if (bid < 4096) {
    const int i = bid * 256 + tid;
    const float4 v = *(const float4*)&x[(size_t)i * 4];
    ushort4 o;
    o.x = f2bf(v.x); o.y = f2bf(v.y); o.z = f2bf(v.z); o.w = f2bf(v.w);
    *(ushort4*)&xb[(size_t)i * 4] = o;
    return;
  }

  __shared__ float tile[32][33];
  const int r  = tid >> 3;
  const int c4 = (tid & 7) * 4;

  const float* W;
  int N, nb, kb, which;
  if (bid < 6144) {
    const int b2 = bid - 4096;
    W = W_kq; N = 2048; nb = (b2 & 63) * 32; kb = (b2 >> 6) * 32; which = 0;
  } else if (bid < 7168) {
    const int b2 = bid - 6144;
    W = W_v;  N = 1024; nb = (b2 & 31) * 32; kb = (b2 >> 5) * 32; which = 1;
  } else {
    const int b2 = bid - 7168;
    W = W_o;  N = 1024; nb = (b2 & 31) * 32; kb = (b2 >> 5) * 32; which = 2;
  }

  const float4 v = *(const float4*)&W[(size_t)(kb + r) * N + nb + c4];
  tile[r][c4 + 0] = v.x; tile[r][c4 + 1] = v.y;
  tile[r][c4 + 2] = v.z; tile[r][c4 + 3] = v.w;
  __syncthreads();

  if (which == 2) {
    half4 o;
    o[0] = (_Float16)tile[c4 + 0][r];
    o[1] = (_Float16)tile[c4 + 1][r];
    o[2] = (_Float16)tile[c4 + 2][r];
    o[3] = (_Float16)tile[c4 + 3][r];
    *(half4*)&wot[(size_t)(nb + r) * 1024 + kb + c4] = o;
  } else {
    ushort4 o;
    o.x = f2bf(tile[c4 + 0][r]);
    o.y = f2bf(tile[c4 + 1][r]);
    o.z = f2bf(tile[c4 + 2][r]);
    o.w = f2bf(tile[c4 + 3][r]);
    unsigned short* dst = (which == 0) ? wcat : wcat + 2097152;
    *(ushort4*)&dst[(size_t)(nb + r) * 1024 + kb + c4] = o;
  }
}

// ---------------- fused kqv GEMM ----------------
// A = xb [4096x1024] bf16, Bt = wcat [3072x1024] bf16
// cols <  2048 : kqb[row][col] = bf16((acc+b_kq[col]) * (col>=1024 ? 0.125 : 1))
// cols >= 2048 : vtb[col-2048][row] = fp16(acc + b_v[col-2048])   (V^T)

__global__ __launch_bounds__(256) void gemm_kqv(
    const unsigned short* __restrict__ A, const unsigned short* __restrict__ Bt,
    const float* __restrict__ b_kq, const float* __restrict__ b_v,
    unsigned short* __restrict__ kqb, _Float16* __restrict__ vtb)
{
  const int tid  = threadIdx.x;
  const int lane = tid & 63;
  const int w    = tid >> 6;
  const int wm   = (w >> 1) * 64;
  const int wn   = (w & 1) * 64;
  const int n0   = blockIdx.x * 128;
  const int m0   = blockIdx.y * 128;
  const int quad = lane >> 4;
  const int l15  = lane & 15;
  const int K    = 1024;

  __shared__ __align__(16) unsigned short As[128 * 64];
  __shared__ __align__(16) unsigned short Bs[128 * 64];

  const int srow = lane >> 3;
  const int sc   = (lane & 7) ^ srow;

  const unsigned short* gA = A  + (size_t)(m0 + w * 32 + srow) * K + sc * 8;
  const unsigned short* gB = Bt + (size_t)(n0 + w * 32 + srow) * K + sc * 8;

  f32x4 acc[4][4] = {};

  for (int k0 = 0; k0 < K; k0 += 64) {
    __syncthreads();
#pragma unroll
    for (int i = 0; i < 4; ++i) {
      load_lds16(gA + (size_t)i * 8 * K + k0, &As[(w * 32 + i * 8) * 64 + lane * 8]);
      load_lds16(gB + (size_t)i * 8 * K + k0, &Bs[(w * 32 + i * 8) * 64 + lane * 8]);
    }
    __syncthreads();
#pragma unroll
    for (int kf = 0; kf < 2; ++kf) {
      frag_ab af[4], bf[4];
#pragma unroll
      for (int t = 0; t < 4; ++t) {
        const int ra = wm + t * 16 + l15;
        const int pa = (kf * 4 + quad) ^ (ra & 7);
        af[t] = *(const frag_ab*)&As[ra * 64 + pa * 8];
        const int rb = wn + t * 16 + l15;
        const int pb = (kf * 4 + quad) ^ (rb & 7);
        bf[t] = *(const frag_ab*)&Bs[rb * 64 + pb * 8];
      }
#pragma unroll
      for (int i = 0; i < 4; ++i)
#pragma unroll
        for (int j = 0; j < 4; ++j)
          acc[i][j] = __builtin_amdgcn_mfma_f32_16x16x32_bf16(
              af[i], bf[j], acc[i][j], 0, 0, 0);
    }
  }

  if (n0 >= 2048) {
#pragma unroll
    for (int i = 0; i < 4; ++i)
#pragma unroll
      for (int j = 0; j < 4; ++j) {
        const int row0 = m0 + wm + i * 16 + quad * 4;
        const int col  = n0 - 2048 + wn + j * 16 + l15;
        const float bv = b_v[col];
        half4 pk;
        pk[0] = (_Float16)(acc[i][j][0] + bv);
        pk[1] = (_Float16)(acc[i][j][1] + bv);
        pk[2] = (_Float16)(acc[i][j][2] + bv);
        pk[3] = (_Float16)(acc[i][j][3] + bv);
        *(half4*)&vtb[(size_t)col * BL + row0] = pk;
      }
  } else {
    const float sc2 = (n0 + wn >= 1024) ? 0.125f : 1.0f;
#pragma unroll
    for (int i = 0; i < 4; ++i)
#pragma unroll
      for (int j = 0; j < 4; ++j) {
        const int row0 = m0 + wm + i * 16 + quad * 4;
        const int col  = n0 + wn + j * 16 + l15;
        const float bv = b_kq[col];
#pragma unroll
        for (int r = 0; r < 4; ++r)
          kqb[(size_t)(row0 + r) * 2048 + col] = f2bf((acc[i][j][r] + bv) * sc2);
      }
  }
}

// ---------------- output GEMM (fp16, 128x64 tiles, 512 blocks) ----------------

__global__ __launch_bounds__(256, 4) void gemm_out(
    const _Float16* __restrict__ A, const _Float16* __restrict__ Bt,
    const float* __restrict__ bias, float* __restrict__ C)
{
  const int tid  = threadIdx.x;
  const int lane = tid & 63;
  const int w    = tid >> 6;
  const int wm   = (w >> 1) * 64;   // 0 / 64
  const int wn   = (w & 1) * 32;    // 0 / 32
  const int n0   = blockIdx.x * 64;
  const int m0   = blockIdx.y * 128;
  const int quad = lane >> 4;
  const int l15  = lane & 15;
  const int K    = 1024;

  __shared__ __align__(16) _Float16 As[128 * 64];
  __shared__ __align__(16) _Float16 Bs[64 * 64];

  const int srow = lane >> 3;
  const int sc   = (lane & 7) ^ srow;

  const _Float16* gA = A  + (size_t)(m0 + w * 32 + srow) * K + sc * 8;
  const _Float16* gB = Bt + (size_t)(n0 + w * 16 + srow) * K + sc * 8;

  f32x4 acc[4][2] = {};

  for (int k0 = 0; k0 < K; k0 += 64) {
    __syncthreads();
#pragma unroll
    for (int i = 0; i < 4; ++i)
      load_lds16(gA + (size_t)i * 8 * K + k0, &As[(w * 32 + i * 8) * 64 + lane * 8]);
#pragma unroll
    for (int i = 0; i < 2; ++i)
      load_lds16(gB + (size_t)i * 8 * K + k0, &Bs[(w * 16 + i * 8) * 64 + lane * 8]);
    __syncthreads();
#pragma unroll
    for (int kf = 0; kf < 2; ++kf) {
      half8 af[4], bf[2];
#pragma unroll
      for (int t = 0; t < 4; ++t) {
        const int ra = wm + t * 16 + l15;
        const int pa = (kf * 4 + quad) ^ (ra & 7);
        af[t] = *(const half8*)&As[ra * 64 + pa * 8];
      }
#pragma unroll
      for (int t = 0; t < 2; ++t) {
        const int rb = wn + t * 16 + l15;
        const int pb = (kf * 4 + quad) ^ (rb & 7);
        bf[t] = *(const half8*)&Bs[rb * 64 + pb * 8];
      }
#pragma unroll
      for (int i = 0; i < 4; ++i)
#pragma unroll
        for (int j = 0; j < 2; ++j)
          acc[i][j] = __builtin_amdgcn_mfma_f32_16x16x32_f16(
              af[i], bf[j], acc[i][j], 0, 0, 0);
    }
  }

#pragma unroll
  for (int i = 0; i < 4; ++i)
#pragma unroll
    for (int j = 0; j < 2; ++j) {
      const int row0 = m0 + wm + i * 16 + quad * 4;
      const int col  = n0 + wn + j * 16 + l15;
      const float bv = bias[col];
#pragma unroll
      for (int r = 0; r < 4; ++r)
        C[(size_t)(row0 + r) * DM + col] = acc[i][j][r] + bv;
    }
}

// ---------------- flash attention ----------------
// kq: bf16 [BL][2048] (k cols 0..1023, q cols 1024..2047 pre-scaled 0.125)
// vt: fp16 [1024][BL] (V^T); att: fp16 [BL][1024]
// Block: 64 q-rows (4 waves x 16), K-tile 128. Lane owns q-row l15 for softmax.
// S^T via mfma_16x16x32_bf16; PV via mfma_16x16x16_f16 with register-local P.

__global__ __launch_bounds__(256, 5) void attn_mfma(
    const unsigned short* __restrict__ kq, const _Float16* __restrict__ vt,
    _Float16* __restrict__ att)
{
  const int tid  = threadIdx.x;
  const int lane = tid & 63;
  const int w    = tid >> 6;
  const int bx   = blockIdx.x;
  const int qt   = 31 - (bx >> 5);   // heavy q-tiles first
  const int bh   = bx & 31;
  const int b    = bh >> 4;
  const int h    = bh & 15;
  const int q0   = qt * 64;
  const int quad = lane >> 4;
  const int l15  = lane & 15;

  __shared__ __align__(16) unsigned short Ks[128 * 64];  // keys x d, bf16 (16KB)
  __shared__ __align__(16) _Float16      Vs[64 * 128];   // d x keys, fp16 (16KB)

  // ---- stage Q (64x64) into Ks region, read frags, then reuse Ks for K ----
#pragma unroll
  for (int i = 0; i < 2; ++i) {
    const int L = i * 256 + tid;        // 0..511
    const int row = L >> 3, c = L & 7;
    const unsigned short* g = kq + (size_t)(b * LSEQ + q0 + row) * 2048
                                 + DM + h * 64 + ((c ^ (row & 7)) * 8);
    load_lds16(g, &Ks[(size_t)L * 8]);
  }
  __syncthreads();
  frag_ab qa[2];
#pragma unroll
  for (int kf = 0; kf < 2; ++kf) {
    const int row = w * 16 + l15;
    const int c = (kf * 4 + quad) ^ (row & 7);
    qa[kf] = *(const frag_ab*)&Ks[row * 64 + c * 8];
  }

  f32x4 oacc[4] = {};
  float mrow = -3e38f, lrow = 0.f;
  const int nk = (qt + 2) >> 1;

  for (int kt = 0; kt < nk; ++kt) {
    const int k0 = kt * 128;
    __syncthreads();   // everyone done reading Ks/Vs (and qa regs loaded)
#pragma unroll
    for (int i = 0; i < 4; ++i) {
      const int L = i * 256 + tid;      // 0..1023
      { // K: 128 rows x 8 chunks of 16B
        const int row = L >> 3, c = L & 7;
        const unsigned short* g = kq + (size_t)(b * LSEQ + k0 + row) * 2048
                                     + h * 64 + ((c ^ (row & 7)) * 8);
        load_lds16(g, &Ks[(size_t)L * 8]);
      }
      { // V^T: 64 rows (d) x 16 chunks of 16B
        const int row = L >> 4, c16 = L & 15;
        const _Float16* g = vt + (size_t)(h * 64 + row) * BL
                               + b * LSEQ + k0 + ((c16 ^ (row & 15)) * 8);
        load_lds16(g, &Vs[(size_t)L * 8]);
      }
    }
    __syncthreads();

    // S^T = K @ Q^T : st[mt][r] = score(key = k0+mt*16+quad*4+r, qrow = l15)
    f32x4 st[8];
#pragma unroll
    for (int mt = 0; mt < 8; ++mt) {
      f32x4 s = {};
#pragma unroll
      for (int kf = 0; kf < 2; ++kf) {
        const int row = mt * 16 + l15;
        const int c = (kf * 4 + quad) ^ (row & 7);
        const frag_ab kfrag = *(const frag_ab*)&Ks[row * 64 + c * 8];
        s = __builtin_amdgcn_mfma_f32_16x16x32_bf16(kfrag, qa[kf], s, 0, 0, 0);
      }
      st[mt] = s;
    }

    if (kt == nk - 1) {   // causal mask (last tile only)
      const int qg = q0 + w * 16 + l15;
#pragma unroll
      for (int mt = 0; mt < 8; ++mt)
#pragma unroll
        for (int r = 0; r < 4; ++r)
          if (k0 + mt * 16 + quad * 4 + r > qg) st[mt][r] = -3e38f;
    }

    // per-lane online softmax for q-row l15 (reduce across the 4 quads)
    float mx = -3e38f;
#pragma unroll
    for (int mt = 0; mt < 8; ++mt)
#pragma unroll
      for (int r = 0; r < 4; ++r) mx = fmaxf(mx, st[mt][r]);
    mx = fmaxf(mx, __shfl_xor(mx, 16));
    mx = fmaxf(mx, __shfl_xor(mx, 32));
    const float mnew  = fmaxf(mrow, mx);
    const float alpha = __expf(mrow - mnew);
    float rsum = 0.f;
#pragma unroll
    for (int mt = 0; mt < 8; ++mt)
#pragma unroll
      for (int r = 0; r < 4; ++r) {
        const float e = __expf(st[mt][r] - mnew);
        st[mt][r] = e;
        rsum += e;
      }
    rsum += __shfl_xor(rsum, 16);
    rsum += __shfl_xor(rsum, 32);
    lrow = lrow * alpha + rsum;
    mrow = mnew;

    // rescale O: alpha for q-row quad*4+r lives in lane (quad*4+r) of this row group
    float aq[4];
#pragma unroll
    for (int r = 0; r < 4; ++r) aq[r] = __shfl(alpha, quad * 4 + r);
#pragma unroll
    for (int dt = 0; dt < 4; ++dt)
#pragma unroll
      for (int r = 0; r < 4; ++r) oacc[dt][r] *= aq[r];

    // O += P @ V : P is register-local (st in C-layout == A-layout of K=16 mfma)
#pragma unroll
    for (int c8 = 0; c8 < 8; ++c8) {
      half4 pf;
      pf[0] = (_Float16)st[c8][0];
      pf[1] = (_Float16)st[c8][1];
      pf[2] = (_Float16)st[c8][2];
      pf[3] = (_Float16)st[c8][3];
#pragma unroll
      for (int dt = 0; dt < 4; ++dt) {
        const int g16 = 2 * c8 + (quad >> 1);
        const half4 vf = *(const half4*)&Vs[(dt * 16 + l15) * 128
                                            + ((g16 ^ l15) << 3) + ((quad & 1) << 2)];
        oacc[dt] = __builtin_amdgcn_mfma_f32_16x16x16f16(pf, vf, oacc[dt], 0, 0, 0);
      }
    }
  }

  // epilogue: lane holds O[qrow=quad*4+r][d=dt*16+l15]; divide by l, store fp16
  float lq[4];
#pragma unroll
  for (int r = 0; r < 4; ++r) lq[r] = 1.0f / __shfl(lrow, quad * 4 + r);
#pragma unroll
  for (int dt = 0; dt < 4; ++dt)
#pragma unroll
    for (int r = 0; r < 4; ++r) {
      const int row = b * LSEQ + q0 + w * 16 + quad * 4 + r;
      const int col = h * 64 + dt * 16 + l15;
      att[(size_t)row * DM + col] = (_Float16)(oacc[dt][r] * lq[r]);
    }
}

// ---------------- launcher ----------------

extern "C" void kernel_launch(void* const* d_in, const int* in_sizes, int n_in,
                              void* d_out, int out_size, void* d_ws, size_t ws_size,
                              hipStream_t stream)
{
  const float* x    = (const float*)d_in[0];
  const float* W_kq = (const float*)d_in[1];
  const float* b_kq = (const float*)d_in[2];
  const float* W_v  = (const float*)d_in[3];
  const float* b_v  = (const float*)d_in[4];
  const float* W_o  = (const float*)d_in[5];
  const float* b_o  = (const float*)d_in[6];

  unsigned short* ws   = (unsigned short*)d_ws;
  unsigned short* xb   = ws;                    // 4096*1024 bf16
  unsigned short* wcat = xb   + 4194304;        // 3072*1024 bf16
  _Float16*       wot  = (_Float16*)(wcat + 3145728);      // 1024*1024 fp16
  unsigned short* kqb  = (unsigned short*)(wot + 1048576); // 4096*2048 bf16
  _Float16*       vtb  = (_Float16*)(kqb + 8388608);       // 1024*4096 fp16
  _Float16*       attb = vtb + 4194304;         // 4096*1024 fp16

  // merged prep (cast + 3 transposes)
  prep_kernel<<<8192, 256, 0, stream>>>(x, xb, W_kq, W_v, W_o, wcat, wot);
  // fused kq + v GEMM (24 x 32 = 768 blocks)
  gemm_kqv<<<dim3(24, 32), 256, 0, stream>>>(xb, wcat, b_kq, b_v, kqb, vtb);
  // attention (1024 blocks)
  attn_mfma<<<1024, 256, 0, stream>>>(kqb, vtb, attb);
  // out = att @ Wo^T + b_o (16 x 32 = 512 blocks, 128x64 tiles)
  gemm_out<<<dim3(16, 32), 256, 0, stream>>>(attb, wot, b_o, (float*)d_out);
}

// Round 7
// 188.005 us; speedup vs baseline: 1.1575x; 1.1575x over previous
//
#include <hip/hip_runtime.h>
#include <cstdint>

// CausalSelfAttention B=2 L=2048 D=1024 H=16 dh=64, fp32 in/out.
// Round 7 = R6 with attn launch_bounds reverted (R6's (256,5) caused VGPR=48
// + scratch spills: FETCH 12->46MB, WRITE 8->69MB) + early fp16 P conversion
// to shrink the live fp32 st[] range.

#define LSEQ 2048
#define DM   1024
#define BL   4096   // B * LSEQ

using frag_ab = __attribute__((ext_vector_type(8))) short;     // 8 bf16
using half8   = __attribute__((ext_vector_type(8))) _Float16;  // 8 fp16
using half4   = __attribute__((ext_vector_type(4))) _Float16;
using f32x4   = __attribute__((ext_vector_type(4))) float;

__device__ __forceinline__ unsigned short f2bf(float f) {
  unsigned int u = __float_as_uint(f);
  u += 0x7fffu + ((u >> 16) & 1u);   // RNE (finite inputs only)
  return (unsigned short)(u >> 16);
}

__device__ __forceinline__ void load_lds16(const void* g, void* l) {
  __builtin_amdgcn_global_load_lds(
      (const __attribute__((address_space(1))) unsigned int*)g,
      (__attribute__((address_space(3))) unsigned int*)l, 16, 0, 0);
}

// ---------------- merged prep kernel ----------------
// bid <  4096          : cast x -> bf16 (1 float4 per thread)
// 4096 <= bid < 6144   : W_kq (1024x2048) -> wcat bf16 [2048x1024]
// 6144 <= bid < 7168   : W_v  (1024x1024) -> wcat+2M bf16
// 7168 <= bid < 8192   : W_o  (1024x1024) -> wot fp16

__global__ __launch_bounds__(256) void prep_kernel(
    const float* __restrict__ x, unsigned short* __restrict__ xb,
    const float* __restrict__ W_kq, const float* __restrict__ W_v,
    const float* __restrict__ W_o,
    unsigned short* __restrict__ wcat, _Float16* __restrict__ wot)
{
  const int bid = blockIdx.x;
  const int tid = threadIdx.x;

  if (bid < 4096) {
    const int i = bid * 256 + tid;
    const float4 v = *(const float4*)&x[(size_t)i * 4];
    ushort4 o;
    o.x = f2bf(v.x); o.y = f2bf(v.y); o.z = f2bf(v.z); o.w = f2bf(v.w);
    *(ushort4*)&xb[(size_t)i * 4] = o;
    return;
  }

  __shared__ float tile[32][33];
  const int r  = tid >> 3;
  const int c4 = (tid & 7) * 4;

  const float* W;
  int N, nb, kb, which;
  if (bid < 6144) {
    const int b2 = bid - 4096;
    W = W_kq; N = 2048; nb = (b2 & 63) * 32; kb = (b2 >> 6) * 32; which = 0;
  } else if (bid < 7168) {
    const int b2 = bid - 6144;
    W = W_v;  N = 1024; nb = (b2 & 31) * 32; kb = (b2 >> 5) * 32; which = 1;
  } else {
    const int b2 = bid - 7168;
    W = W_o;  N = 1024; nb = (b2 & 31) * 32; kb = (b2 >> 5) * 32; which = 2;
  }

  const float4 v = *(const float4*)&W[(size_t)(kb + r) * N + nb + c4];
  tile[r][c4 + 0] = v.x; tile[r][c4 + 1] = v.y;
  tile[r][c4 + 2] = v.z; tile[r][c4 + 3] = v.w;
  __syncthreads();

  if (which == 2) {
    half4 o;
    o[0] = (_Float16)tile[c4 + 0][r];
    o[1] = (_Float16)tile[c4 + 1][r];
    o[2] = (_Float16)tile[c4 + 2][r];
    o[3] = (_Float16)tile[c4 + 3][r];
    *(half4*)&wot[(size_t)(nb + r) * 1024 + kb + c4] = o;
  } else {
    ushort4 o;
    o.x = f2bf(tile[c4 + 0][r]);
    o.y = f2bf(tile[c4 + 1][r]);
    o.z = f2bf(tile[c4 + 2][r]);
    o.w = f2bf(tile[c4 + 3][r]);
    unsigned short* dst = (which == 0) ? wcat : wcat + 2097152;
    *(ushort4*)&dst[(size_t)(nb + r) * 1024 + kb + c4] = o;
  }
}

// ---------------- fused kqv GEMM ----------------
// A = xb [4096x1024] bf16, Bt = wcat [3072x1024] bf16
// cols <  2048 : kqb[row][col] = bf16((acc+b_kq[col]) * (col>=1024 ? 0.125 : 1))
// cols >= 2048 : vtb[col-2048][row] = fp16(acc + b_v[col-2048])   (V^T)

__global__ __launch_bounds__(256) void gemm_kqv(
    const unsigned short* __restrict__ A, const unsigned short* __restrict__ Bt,
    const float* __restrict__ b_kq, const float* __restrict__ b_v,
    unsigned short* __restrict__ kqb, _Float16* __restrict__ vtb)
{
  const int tid  = threadIdx.x;
  const int lane = tid & 63;
  const int w    = tid >> 6;
  const int wm   = (w >> 1) * 64;
  const int wn   = (w & 1) * 64;
  const int n0   = blockIdx.x * 128;
  const int m0   = blockIdx.y * 128;
  const int quad = lane >> 4;
  const int l15  = lane & 15;
  const int K    = 1024;

  __shared__ __align__(16) unsigned short As[128 * 64];
  __shared__ __align__(16) unsigned short Bs[128 * 64];

  const int srow = lane >> 3;
  const int sc   = (lane & 7) ^ srow;

  const unsigned short* gA = A  + (size_t)(m0 + w * 32 + srow) * K + sc * 8;
  const unsigned short* gB = Bt + (size_t)(n0 + w * 32 + srow) * K + sc * 8;

  f32x4 acc[4][4] = {};

  for (int k0 = 0; k0 < K; k0 += 64) {
    __syncthreads();
#pragma unroll
    for (int i = 0; i < 4; ++i) {
      load_lds16(gA + (size_t)i * 8 * K + k0, &As[(w * 32 + i * 8) * 64 + lane * 8]);
      load_lds16(gB + (size_t)i * 8 * K + k0, &Bs[(w * 32 + i * 8) * 64 + lane * 8]);
    }
    __syncthreads();
#pragma unroll
    for (int kf = 0; kf < 2; ++kf) {
      frag_ab af[4], bf[4];
#pragma unroll
      for (int t = 0; t < 4; ++t) {
        const int ra = wm + t * 16 + l15;
        const int pa = (kf * 4 + quad) ^ (ra & 7);
        af[t] = *(const frag_ab*)&As[ra * 64 + pa * 8];
        const int rb = wn + t * 16 + l15;
        const int pb = (kf * 4 + quad) ^ (rb & 7);
        bf[t] = *(const frag_ab*)&Bs[rb * 64 + pb * 8];
      }
#pragma unroll
      for (int i = 0; i < 4; ++i)
#pragma unroll
        for (int j = 0; j < 4; ++j)
          acc[i][j] = __builtin_amdgcn_mfma_f32_16x16x32_bf16(
              af[i], bf[j], acc[i][j], 0, 0, 0);
    }
  }

  if (n0 >= 2048) {
#pragma unroll
    for (int i = 0; i < 4; ++i)
#pragma unroll
      for (int j = 0; j < 4; ++j) {
        const int row0 = m0 + wm + i * 16 + quad * 4;
        const int col  = n0 - 2048 + wn + j * 16 + l15;
        const float bv = b_v[col];
        half4 pk;
        pk[0] = (_Float16)(acc[i][j][0] + bv);
        pk[1] = (_Float16)(acc[i][j][1] + bv);
        pk[2] = (_Float16)(acc[i][j][2] + bv);
        pk[3] = (_Float16)(acc[i][j][3] + bv);
        *(half4*)&vtb[(size_t)col * BL + row0] = pk;
      }
  } else {
    const float sc2 = (n0 + wn >= 1024) ? 0.125f : 1.0f;
#pragma unroll
    for (int i = 0; i < 4; ++i)
#pragma unroll
      for (int j = 0; j < 4; ++j) {
        const int row0 = m0 + wm + i * 16 + quad * 4;
        const int col  = n0 + wn + j * 16 + l15;
        const float bv = b_kq[col];
#pragma unroll
        for (int r = 0; r < 4; ++r)
          kqb[(size_t)(row0 + r) * 2048 + col] = f2bf((acc[i][j][r] + bv) * sc2);
      }
  }
}

// ---------------- output GEMM (fp16, 128x64 tiles, 512 blocks) ----------------

__global__ __launch_bounds__(256, 4) void gemm_out(
    const _Float16* __restrict__ A, const _Float16* __restrict__ Bt,
    const float* __restrict__ bias, float* __restrict__ C)
{
  const int tid  = threadIdx.x;
  const int lane = tid & 63;
  const int w    = tid >> 6;
  const int wm   = (w >> 1) * 64;   // 0 / 64
  const int wn   = (w & 1) * 32;    // 0 / 32
  const int n0   = blockIdx.x * 64;
  const int m0   = blockIdx.y * 128;
  const int quad = lane >> 4;
  const int l15  = lane & 15;
  const int K    = 1024;

  __shared__ __align__(16) _Float16 As[128 * 64];
  __shared__ __align__(16) _Float16 Bs[64 * 64];

  const int srow = lane >> 3;
  const int sc   = (lane & 7) ^ srow;

  const _Float16* gA = A  + (size_t)(m0 + w * 32 + srow) * K + sc * 8;
  const _Float16* gB = Bt + (size_t)(n0 + w * 16 + srow) * K + sc * 8;

  f32x4 acc[4][2] = {};

  for (int k0 = 0; k0 < K; k0 += 64) {
    __syncthreads();
#pragma unroll
    for (int i = 0; i < 4; ++i)
      load_lds16(gA + (size_t)i * 8 * K + k0, &As[(w * 32 + i * 8) * 64 + lane * 8]);
#pragma unroll
    for (int i = 0; i < 2; ++i)
      load_lds16(gB + (size_t)i * 8 * K + k0, &Bs[(w * 16 + i * 8) * 64 + lane * 8]);
    __syncthreads();
#pragma unroll
    for (int kf = 0; kf < 2; ++kf) {
      half8 af[4], bf[2];
#pragma unroll
      for (int t = 0; t < 4; ++t) {
        const int ra = wm + t * 16 + l15;
        const int pa = (kf * 4 + quad) ^ (ra & 7);
        af[t] = *(const half8*)&As[ra * 64 + pa * 8];
      }
#pragma unroll
      for (int t = 0; t < 2; ++t) {
        const int rb = wn + t * 16 + l15;
        const int pb = (kf * 4 + quad) ^ (rb & 7);
        bf[t] = *(const half8*)&Bs[rb * 64 + pb * 8];
      }
#pragma unroll
      for (int i = 0; i < 4; ++i)
#pragma unroll
        for (int j = 0; j < 2; ++j)
          acc[i][j] = __builtin_amdgcn_mfma_f32_16x16x32_f16(
              af[i], bf[j], acc[i][j], 0, 0, 0);
    }
  }

#pragma unroll
  for (int i = 0; i < 4; ++i)
#pragma unroll
    for (int j = 0; j < 2; ++j) {
      const int row0 = m0 + wm + i * 16 + quad * 4;
      const int col  = n0 + wn + j * 16 + l15;
      const float bv = bias[col];
#pragma unroll
      for (int r = 0; r < 4; ++r)
        C[(size_t)(row0 + r) * DM + col] = acc[i][j][r] + bv;
    }
}

// ---------------- flash attention ----------------
// kq: bf16 [BL][2048] (k cols 0..1023, q cols 1024..2047 pre-scaled 0.125)
// vt: fp16 [1024][BL] (V^T); att: fp16 [BL][1024]
// Block: 64 q-rows (4 waves x 16), K-tile 128. Lane owns q-row l15 for softmax.
// S^T via mfma_16x16x32_bf16; PV via mfma_16x16x16_f16 with register-local P.
// NOTE: no min-waves launch bound — (256,5) spilled catastrophically (R6).

__global__ __launch_bounds__(256) void attn_mfma(
    const unsigned short* __restrict__ kq, const _Float16* __restrict__ vt,
    _Float16* __restrict__ att)
{
  const int tid  = threadIdx.x;
  const int lane = tid & 63;
  const int w    = tid >> 6;
  const int bx   = blockIdx.x;
  const int qt   = 31 - (bx >> 5);   // heavy q-tiles first
  const int bh   = bx & 31;
  const int b    = bh >> 4;
  const int h    = bh & 15;
  const int q0   = qt * 64;
  const int quad = lane >> 4;
  const int l15  = lane & 15;

  __shared__ __align__(16) unsigned short Ks[128 * 64];  // keys x d, bf16 (16KB)
  __shared__ __align__(16) _Float16      Vs[64 * 128];   // d x keys, fp16 (16KB)

  // ---- stage Q (64x64) into Ks region, read frags, then reuse Ks for K ----
#pragma unroll
  for (int i = 0; i < 2; ++i) {
    const int L = i * 256 + tid;        // 0..511
    const int row = L >> 3, c = L & 7;
    const unsigned short* g = kq + (size_t)(b * LSEQ + q0 + row) * 2048
                                 + DM + h * 64 + ((c ^ (row & 7)) * 8);
    load_lds16(g, &Ks[(size_t)L * 8]);
  }
  __syncthreads();
  frag_ab qa[2];
#pragma unroll
  for (int kf = 0; kf < 2; ++kf) {
    const int row = w * 16 + l15;
    const int c = (kf * 4 + quad) ^ (row & 7);
    qa[kf] = *(const frag_ab*)&Ks[row * 64 + c * 8];
  }

  f32x4 oacc[4] = {};
  float mrow = -3e38f, lrow = 0.f;
  const int nk = (qt + 2) >> 1;

  for (int kt = 0; kt < nk; ++kt) {
    const int k0 = kt * 128;
    __syncthreads();   // everyone done reading Ks/Vs (and qa regs loaded)
#pragma unroll
    for (int i = 0; i < 4; ++i) {
      const int L = i * 256 + tid;      // 0..1023
      { // K: 128 rows x 8 chunks of 16B
        const int row = L >> 3, c = L & 7;
        const unsigned short* g = kq + (size_t)(b * LSEQ + k0 + row) * 2048
                                     + h * 64 + ((c ^ (row & 7)) * 8);
        load_lds16(g, &Ks[(size_t)L * 8]);
      }
      { // V^T: 64 rows (d) x 16 chunks of 16B
        const int row = L >> 4, c16 = L & 15;
        const _Float16* g = vt + (size_t)(h * 64 + row) * BL
                               + b * LSEQ + k0 + ((c16 ^ (row & 15)) * 8);
        load_lds16(g, &Vs[(size_t)L * 8]);
      }
    }
    __syncthreads();

    // S^T = K @ Q^T : st[mt][r] = score(key = k0+mt*16+quad*4+r, qrow = l15)
    f32x4 st[8];
#pragma unroll
    for (int mt = 0; mt < 8; ++mt) {
      f32x4 s = {};
#pragma unroll
      for (int kf = 0; kf < 2; ++kf) {
        const int row = mt * 16 + l15;
        const int c = (kf * 4 + quad) ^ (row & 7);
        const frag_ab kfrag = *(const frag_ab*)&Ks[row * 64 + c * 8];
        s = __builtin_amdgcn_mfma_f32_16x16x32_bf16(kfrag, qa[kf], s, 0, 0, 0);
      }
      st[mt] = s;
    }

    if (kt == nk - 1) {   // causal mask (last tile only)
      const int qg = q0 + w * 16 + l15;
#pragma unroll
      for (int mt = 0; mt < 8; ++mt)
#pragma unroll
        for (int r = 0; r < 4; ++r)
          if (k0 + mt * 16 + quad * 4 + r > qg) st[mt][r] = -3e38f;
    }

    // per-lane online softmax for q-row l15 (reduce across the 4 quads)
    float mx = -3e38f;
#pragma unroll
    for (int mt = 0; mt < 8; ++mt)
#pragma unroll
      for (int r = 0; r < 4; ++r) mx = fmaxf(mx, st[mt][r]);
    mx = fmaxf(mx, __shfl_xor(mx, 16));
    mx = fmaxf(mx, __shfl_xor(mx, 32));
    const float mnew  = fmaxf(mrow, mx);
    const float alpha = __expf(mrow - mnew);
    // exp + immediate fp16 convert (frees the fp32 st[] early)
    half4 pf[8];
    float rsum = 0.f;
#pragma unroll
    for (int mt = 0; mt < 8; ++mt)
#pragma unroll
      for (int r = 0; r < 4; ++r) {
        const float e = __expf(st[mt][r] - mnew);
        rsum += e;
        pf[mt][r] = (_Float16)e;
      }
    rsum += __shfl_xor(rsum, 16);
    rsum += __shfl_xor(rsum, 32);
    lrow = lrow * alpha + rsum;
    mrow = mnew;

    // rescale O: alpha for q-row quad*4+r lives in lane (quad*4+r) of this row group
    float aq[4];
#pragma unroll
    for (int r = 0; r < 4; ++r) aq[r] = __shfl(alpha, quad * 4 + r);
#pragma unroll
    for (int dt = 0; dt < 4; ++dt)
#pragma unroll
      for (int r = 0; r < 4; ++r) oacc[dt][r] *= aq[r];

    // O += P @ V : P is register-local (st C-layout == A-layout of K=16 mfma)
#pragma unroll
    for (int c8 = 0; c8 < 8; ++c8) {
#pragma unroll
      for (int dt = 0; dt < 4; ++dt) {
        const int g16 = 2 * c8 + (quad >> 1);
        const half4 vf = *(const half4*)&Vs[(dt * 16 + l15) * 128
                                            + ((g16 ^ l15) << 3) + ((quad & 1) << 2)];
        oacc[dt] = __builtin_amdgcn_mfma_f32_16x16x16f16(pf[c8], vf, oacc[dt], 0, 0, 0);
      }
    }
  }

  // epilogue: lane holds O[qrow=quad*4+r][d=dt*16+l15]; divide by l, store fp16
  float lq[4];
#pragma unroll
  for (int r = 0; r < 4; ++r) lq[r] = 1.0f / __shfl(lrow, quad * 4 + r);
#pragma unroll
  for (int dt = 0; dt < 4; ++dt)
#pragma unroll
    for (int r = 0; r < 4; ++r) {
      const int row = b * LSEQ + q0 + w * 16 + quad * 4 + r;
      const int col = h * 64 + dt * 16 + l15;
      att[(size_t)row * DM + col] = (_Float16)(oacc[dt][r] * lq[r]);
    }
}

// ---------------- launcher ----------------

extern "C" void kernel_launch(void* const* d_in, const int* in_sizes, int n_in,
                              void* d_out, int out_size, void* d_ws, size_t ws_size,
                              hipStream_t stream)
{
  const float* x    = (const float*)d_in[0];
  const float* W_kq = (const float*)d_in[1];
  const float* b_kq = (const float*)d_in[2];
  const float* W_v  = (const float*)d_in[3];
  const float* b_v  = (const float*)d_in[4];
  const float* W_o  = (const float*)d_in[5];
  const float* b_o  = (const float*)d_in[6];

  unsigned short* ws   = (unsigned short*)d_ws;
  unsigned short* xb   = ws;                    // 4096*1024 bf16
  unsigned short* wcat = xb   + 4194304;        // 3072*1024 bf16
  _Float16*       wot  = (_Float16*)(wcat + 3145728);      // 1024*1024 fp16
  unsigned short* kqb  = (unsigned short*)(wot + 1048576); // 4096*2048 bf16
  _Float16*       vtb  = (_Float16*)(kqb + 8388608);       // 1024*4096 fp16
  _Float16*       attb = vtb + 4194304;         // 4096*1024 fp16

  // merged prep (cast + 3 transposes)
  prep_kernel<<<8192, 256, 0, stream>>>(x, xb, W_kq, W_v, W_o, wcat, wot);
  // fused kq + v GEMM (24 x 32 = 768 blocks)
  gemm_kqv<<<dim3(24, 32), 256, 0, stream>>>(xb, wcat, b_kq, b_v, kqb, vtb);
  // attention (1024 blocks)
  attn_mfma<<<1024, 256, 0, stream>>>(kqb, vtb, attb);
  // out = att @ Wo^T + b_o (16 x 32 = 512 blocks, 128x64 tiles)
  gemm_out<<<dim3(16, 32), 256, 0, stream>>>(attb, wot, b_o, (float*)d_out);
}